// Round 1
// baseline (2158.799 us; speedup 1.0000x reference)
//
#include <hip/hip_runtime.h>

// LTC RNN (LiquidNeuralNetwork): B=512, S=512, H=128, 2 layers, RK4.
// Strategy: persistent kernel, 32 blocks x 512 threads (8 waves), 16 batch/block.
// All matvecs as f16 MFMA 16x16x32 (fp32 accum): D = W[256x128] * hh^T[128x16].
// Wave w owns tile pair (gate rows 16w..16w+15, rec rows same) -> elementwise RK
// math stays in-lane. hh cycles through LDS f16 buffers (B-frag layout).
// Weights pre-packed to A-fragments in d_ws by prep kernel, held in VGPRs.

typedef _Float16 f16;
typedef _Float16 f16x2 __attribute__((ext_vector_type(2)));
typedef _Float16 f16x4 __attribute__((ext_vector_type(4)));
typedef _Float16 f16x8 __attribute__((ext_vector_type(8)));
typedef float f32x4 __attribute__((ext_vector_type(4)));

#define NSTEP 512
#define OFF_A0 0
#define OFF_A1 32768
#define OFF_AIO 65536
#define OFF_AX 98304
#define W_TOTAL 122880

__device__ __forceinline__ float rcp_f(float x) { return __builtin_amdgcn_rcpf(x); }
__device__ __forceinline__ float tanh_f(float x) {
  float e = __expf(2.f * x);
  return 1.f - 2.f * rcp_f(e + 1.f);
}
// sigmoid(t) for t in [-1,1] (t = tanh(...)): 0.5 + 0.5*tanh(t/2) odd Taylor, |err|<3e-6
__device__ __forceinline__ float sig_poly(float t) {
  float s = t * t;
  float p = fmaf(s, 2.1356861e-5f, -2.1081349e-4f);
  p = fmaf(s, p, 2.0833333e-3f);
  p = fmaf(s, p, -2.0833333e-2f);
  p = fmaf(s, p, 0.25f);
  return fmaf(t, p, 0.5f);
}

// Pack all recurrent-loop weights into f16 MFMA A-fragments.
// A-frag layout (16x16x32): A[m=lane&15][k=(lane>>4)*8+j], tile rows = 16w..16w+15.
// A0 @0      [w8][sel2][kc4][lane64][j8]  sel0=Wg0 h-part, sel1=Wrec0
// A1 @32768  same                          sel0=Wg1 h-part, sel1=Wrec1
// AIO@65536  same                          sel0=Win1,       sel1=Wg1 x-part
// AX @98304  [w8][sel2][kc3][lane64][j8]  sel0=Win0,       sel1=Wg0 x-part (K=96)
__global__ __launch_bounds__(256) void prep_kernel(
    const float* __restrict__ Win0, const float* __restrict__ Wrec0,
    const float* __restrict__ Wg0, const float* __restrict__ Win1,
    const float* __restrict__ Wrec1, const float* __restrict__ Wg1,
    f16* __restrict__ W) {
  int i = blockIdx.x * 256 + threadIdx.x;
  if (i >= W_TOTAL) return;
  if (i < OFF_AX) {
    int sec = i >> 15;
    int r = i & 32767;
    int j = r & 7, lane = (r >> 3) & 63, kc = (r >> 9) & 3, sel = (r >> 11) & 1,
        w = (r >> 12) & 7;
    int row = w * 16 + (lane & 15);
    int k = kc * 32 + ((lane >> 4) << 3) + j;
    float v;
    if (sec == 0)
      v = sel ? Wrec0[row * 128 + k] : Wg0[row * 224 + 96 + k];
    else if (sec == 1)
      v = sel ? Wrec1[row * 128 + k] : Wg1[row * 256 + 128 + k];
    else
      v = sel ? Wg1[row * 256 + k] : Win1[row * 128 + k];
    W[i] = (f16)v;
  } else {
    int r = i - OFF_AX;
    int j = r & 7, lane = (r >> 3) & 63, g = r >> 9;
    int kc = g % 3, sg = g / 3;
    int sel = sg & 1, w = sg >> 1;
    int row = w * 16 + (lane & 15);
    int k = kc * 32 + ((lane >> 4) << 3) + j;
    W[i] = (f16)(sel ? Wg0[row * 224 + k] : Win0[row * 96 + k]);
  }
}

#define MFMA16(A, B, C) __builtin_amdgcn_mfma_f32_16x16x32_f16((A), (B), (C), 0, 0, 0)
#define ZERO4 ((f32x4){0.f, 0.f, 0.f, 0.f})

// hh LDS layout: [col c=batch][h-dim j], stride 136 f16 (272B = 17*16, 16B aligned)
#define RK_MM(AMAT, SRC, GA, RA)                                         \
  {                                                                      \
    _Pragma("unroll") for (int kc_ = 0; kc_ < 4; ++kc_) {                \
      f16x8 bf_ = *(const f16x8*)((SRC) + c * 136 + kc_ * 32 + 8 * q);   \
      GA = MFMA16(AMAT[0][kc_], bf_, GA);                                \
      RA = MFMA16(AMAT[1][kc_], bf_, RA);                                \
    }                                                                    \
  }

#define GATEK(KV, GA, RA, UU, GG, IT)                                    \
  {                                                                      \
    _Pragma("unroll") for (int r_ = 0; r_ < 4; ++r_) {                   \
      float th_ = tanh_f(GA[r_] + GG[r_]);                               \
      float gt_ = sig_poly(th_);                                         \
      KV[r_] = fmaf(gt_, RA[r_], fmaf(-IT[r_], hhc[r_], UU[r_]));        \
    }                                                                    \
  }

#define WRITE_HH(DST, V)                                                 \
  {                                                                      \
    f16x4 hv_;                                                           \
    _Pragma("unroll") for (int r_ = 0; r_ < 4; ++r_) hv_[r_] = (f16)V[r_]; \
    *(f16x4*)((DST) + c * 136 + jbase) = hv_;                            \
  }

__global__ __launch_bounds__(512) void ltc_kernel(
    const float* __restrict__ seq, const float* __restrict__ ctx,
    const float* __restrict__ tau0p, const float* __restrict__ bg0p,
    const float* __restrict__ tau1p, const float* __restrict__ bg1p,
    const float* __restrict__ W1, const float* __restrict__ b1,
    const float* __restrict__ W2, const float* __restrict__ b2,
    const f16* __restrict__ W, float* __restrict__ out) {
  __shared__ __align__(16) char smem[3 * 4352 + 2 * 2304];
  f16* hb0 = (f16*)(smem);
  f16* hb1 = (f16*)(smem + 4352);
  f16* hb2 = (f16*)(smem + 2 * 4352);
  f16* xbA = (f16*)(smem + 3 * 4352);          // [16][72] f16 seq tile, t even
  f16* xbB = (f16*)(smem + 3 * 4352 + 2304);   // t odd

  const int tid = threadIdx.x;
  const int w = tid >> 6, lane = tid & 63;
  const int q = lane >> 4, c = lane & 15;
  const int bg = blockIdx.x;
  const int jbase = w * 16 + q * 4;  // this lane's h-unit rows: jbase..jbase+3

  // ---- weight fragments -> VGPRs (held for whole kernel) ----
  f16x8 a0[2][4], a1[2][4], aio[2][4], ax[2][3];
#pragma unroll
  for (int sel = 0; sel < 2; ++sel) {
#pragma unroll
    for (int kc = 0; kc < 4; ++kc) {
      int o = (((w * 2 + sel) * 4 + kc) * 64 + lane) * 8;
      a0[sel][kc] = *(const f16x8*)(W + OFF_A0 + o);
      a1[sel][kc] = *(const f16x8*)(W + OFF_A1 + o);
      aio[sel][kc] = *(const f16x8*)(W + OFF_AIO + o);
    }
#pragma unroll
    for (int kc = 0; kc < 3; ++kc)
      ax[sel][kc] = *(const f16x8*)(W + OFF_AX + (((w * 2 + sel) * 3 + kc) * 64 + lane) * 8);
  }

  // ctx B-fragment (x-feats 64..95), t-invariant
  f16x8 bctx;
  {
    const float* cp = ctx + (bg * 16 + c) * 32 + 8 * q;
#pragma unroll
    for (int j = 0; j < 8; ++j) bctx[j] = (f16)cp[j];
  }

  // per-lane params for rows jbase..jbase+3
  f32x4 it0, it1, bg0v, bg1v;
#pragma unroll
  for (int r = 0; r < 4; ++r) {
    float t0 = tau0p[jbase + r], t1 = tau1p[jbase + r];
    it0[r] = 1.f / (logf(1.f + __expf(t0)) + 1.f);  // 1/(softplus+1)
    it1[r] = 1.f / (logf(1.f + __expf(t1)) + 1.f);
    bg0v[r] = bg0p[jbase + r];
    bg1v[r] = bg1p[jbase + r];
  }

  f32x4 h0 = ZERO4, h1 = ZERO4;
  *(f16x4*)(hb0 + c * 136 + jbase) = (f16x4){0, 0, 0, 0};  // h0 = 0 into LDS

  // stage seq for t=0
  const int bs = tid >> 5, fp = tid & 31;
  const size_t seqbase = ((size_t)(bg * 16 + bs)) * NSTEP * 64 + 2 * fp;
  {
    float2 sv = *(const float2*)(seq + seqbase);
    *(f16x2*)(xbA + bs * 72 + 2 * fp) = (f16x2){(f16)sv.x, (f16)sv.y};
  }
  __syncthreads();

  f16* xcur = xbA;
  f16* xnxt = xbB;
  f32x4 u0, gx0, u1, g1x, ksum, hhc, kk;
  float2 sqpre = {0.f, 0.f};

#pragma unroll 1
  for (int t = 0; t < NSTEP; ++t) {
    // ================= slot 1: x-proj(t) + L0 RK stage 1 =================
    if (t + 1 < NSTEP) sqpre = *(const float2*)(seq + seqbase + (size_t)(t + 1) * 64);
    f32x4 xu = ZERO4, xg = ZERO4;
    {
      f16x8 bx0 = *(const f16x8*)(xcur + c * 72 + 8 * q);
      f16x8 bx1 = *(const f16x8*)(xcur + c * 72 + 32 + 8 * q);
      xu = MFMA16(ax[0][0], bx0, xu);
      xg = MFMA16(ax[1][0], bx0, xg);
      xu = MFMA16(ax[0][1], bx1, xu);
      xg = MFMA16(ax[1][1], bx1, xg);
      xu = MFMA16(ax[0][2], bctx, xu);
      xg = MFMA16(ax[1][2], bctx, xg);
    }
    f32x4 ga = ZERO4, ra = ZERO4;
    RK_MM(a0, hb0, ga, ra);
#pragma unroll
    for (int r = 0; r < 4; ++r) {
      u0[r] = xu[r];
      gx0[r] = xg[r] + bg0v[r];
    }
    hhc = h0;
    GATEK(kk, ga, ra, u0, gx0, it0);
#pragma unroll
    for (int r = 0; r < 4; ++r) {
      ksum[r] = kk[r];
      hhc[r] = fmaf(0.5f, kk[r], h0[r]);
    }
    WRITE_HH(hb1, hhc);
    __syncthreads();

    // ================= slot 2: L0 RK stage 2 + stage seq(t+1) ============
    if (t + 1 < NSTEP)
      *(f16x2*)(xnxt + bs * 72 + 2 * fp) = (f16x2){(f16)sqpre.x, (f16)sqpre.y};
    ga = ZERO4; ra = ZERO4;
    RK_MM(a0, hb1, ga, ra);
    GATEK(kk, ga, ra, u0, gx0, it0);
#pragma unroll
    for (int r = 0; r < 4; ++r) {
      ksum[r] = fmaf(2.f, kk[r], ksum[r]);
      hhc[r] = fmaf(0.5f, kk[r], h0[r]);
    }
    WRITE_HH(hb2, hhc);
    __syncthreads();

    // ================= slot 3: L0 RK stage 3 =============================
    ga = ZERO4; ra = ZERO4;
    RK_MM(a0, hb2, ga, ra);
    GATEK(kk, ga, ra, u0, gx0, it0);
#pragma unroll
    for (int r = 0; r < 4; ++r) {
      ksum[r] = fmaf(2.f, kk[r], ksum[r]);
      hhc[r] = h0[r] + kk[r];
    }
    WRITE_HH(hb1, hhc);
    __syncthreads();

    // ================= slot 4: L0 RK stage 4 -> h0_new ===================
    ga = ZERO4; ra = ZERO4;
    RK_MM(a0, hb1, ga, ra);
    GATEK(kk, ga, ra, u0, gx0, it0);
#pragma unroll
    for (int r = 0; r < 4; ++r) {
      ksum[r] += kk[r];
      h0[r] = tanh_f(fmaf(ksum[r], 0.16666667f, h0[r]));
    }
    WRITE_HH(hb0, h0);
    __syncthreads();

    // ================= slot 5: L1 input projection + stage h1 ============
    {
      f32x4 pu = ZERO4, pg = ZERO4;
      RK_MM(aio, hb0, pu, pg);
#pragma unroll
      for (int r = 0; r < 4; ++r) {
        u1[r] = pu[r];
        g1x[r] = pg[r] + bg1v[r];
      }
    }
    WRITE_HH(hb1, h1);
    __syncthreads();

    // ================= slot 6: L1 RK stage 1 =============================
    ga = ZERO4; ra = ZERO4;
    RK_MM(a1, hb1, ga, ra);
    hhc = h1;
    GATEK(kk, ga, ra, u1, g1x, it1);
#pragma unroll
    for (int r = 0; r < 4; ++r) {
      ksum[r] = kk[r];
      hhc[r] = fmaf(0.5f, kk[r], h1[r]);
    }
    WRITE_HH(hb2, hhc);
    __syncthreads();

    // ================= slot 7: L1 RK stage 2 =============================
    ga = ZERO4; ra = ZERO4;
    RK_MM(a1, hb2, ga, ra);
    GATEK(kk, ga, ra, u1, g1x, it1);
#pragma unroll
    for (int r = 0; r < 4; ++r) {
      ksum[r] = fmaf(2.f, kk[r], ksum[r]);
      hhc[r] = fmaf(0.5f, kk[r], h1[r]);
    }
    WRITE_HH(hb1, hhc);
    __syncthreads();

    // ================= slot 8: L1 RK stage 3 =============================
    ga = ZERO4; ra = ZERO4;
    RK_MM(a1, hb1, ga, ra);
    GATEK(kk, ga, ra, u1, g1x, it1);
#pragma unroll
    for (int r = 0; r < 4; ++r) {
      ksum[r] = fmaf(2.f, kk[r], ksum[r]);
      hhc[r] = h1[r] + kk[r];
    }
    WRITE_HH(hb2, hhc);
    __syncthreads();

    // ================= slot 9: L1 RK stage 4 -> h1_new (no barrier) ======
    ga = ZERO4; ra = ZERO4;
    RK_MM(a1, hb2, ga, ra);
    GATEK(kk, ga, ra, u1, g1x, it1);
#pragma unroll
    for (int r = 0; r < 4; ++r) {
      ksum[r] += kk[r];
      h1[r] = tanh_f(fmaf(ksum[r], 0.16666667f, h1[r]));
    }
    // no barrier: next slot 1 touches only hb0(read)/hb1(write), both safe.

    f16* tx = xcur;
    xcur = xnxt;
    xnxt = tx;
  }

  // ======================= classifier epilogue ===========================
  __syncthreads();
  float* h1f = (float*)smem;  // [16][132] f32
  *(f32x4*)(h1f + c * 132 + jbase) = h1;
  __syncthreads();
  float* z1 = (float*)(smem + 16 * 132 * 4);  // [16][64] f32
  {
    int b = tid >> 5, o = tid & 31;
#pragma unroll
    for (int hlf = 0; hlf < 2; ++hlf) {
      int oo = o + 32 * hlf;
      const float* wr = W1 + oo * 128;
      const float* hr = h1f + b * 132;
      float s = 0.f;
#pragma unroll
      for (int j = 0; j < 128; j += 4) {
        f32x4 wv = *(const f32x4*)(wr + j);
        f32x4 hv = *(const f32x4*)(hr + j);
        s += wv[0] * hv[0] + wv[1] * hv[1] + wv[2] * hv[2] + wv[3] * hv[3];
      }
      s += b1[oo];
      z1[b * 64 + oo] = fmaxf(s, 0.f);
    }
  }
  __syncthreads();
  if (tid < 16) {
    float s = b2[0];
#pragma unroll
    for (int o = 0; o < 64; ++o) s += z1[tid * 64 + o] * W2[o];
    out[bg * 16 + tid] = rcp_f(1.f + __expf(-s));
  }
}

extern "C" void kernel_launch(void* const* d_in, const int* in_sizes, int n_in,
                              void* d_out, int out_size, void* d_ws, size_t ws_size,
                              hipStream_t stream) {
  (void)in_sizes; (void)n_in; (void)out_size; (void)ws_size;
  const float* seq = (const float*)d_in[0];
  const float* ctx = (const float*)d_in[1];
  const float* tau0 = (const float*)d_in[2];
  const float* Win0 = (const float*)d_in[3];
  const float* Wrec0 = (const float*)d_in[4];
  const float* Wg0 = (const float*)d_in[5];
  const float* bg0 = (const float*)d_in[6];
  const float* tau1 = (const float*)d_in[7];
  const float* Win1 = (const float*)d_in[8];
  const float* Wrec1 = (const float*)d_in[9];
  const float* Wg1 = (const float*)d_in[10];
  const float* bg1 = (const float*)d_in[11];
  const float* W1 = (const float*)d_in[12];
  const float* b1 = (const float*)d_in[13];
  const float* W2 = (const float*)d_in[14];
  const float* b2 = (const float*)d_in[15];
  f16* W = (f16*)d_ws;  // 245760 B of packed fragments

  prep_kernel<<<480, 256, 0, stream>>>(Win0, Wrec0, Wg0, Win1, Wrec1, Wg1, W);
  ltc_kernel<<<32, 512, 0, stream>>>(seq, ctx, tau0, bg0, tau1, bg1, W1, b1, W2,
                                     b2, W, (float*)d_out);
}

// Round 3
// 1963.433 us; speedup vs baseline: 1.0995x; 1.0995x over previous
//
#include <hip/hip_runtime.h>

// LTC RNN (LiquidNeuralNetwork): B=512, S=512, H=128, 2 layers, RK4.
// Round 2b: layer-pipelined persistent kernel. 32 blocks x 512 threads (8 waves).
// Waves 0-3 = layer 0 at step t; waves 4-7 = layer 1 at step t-1 (lag-1 pipeline;
// h1 never feeds h0, so the chains overlap). Each wave owns 4 row-tiles (2 gate +
// 2 rec, rows 32w..32w+31), so each B-frag LDS read amortizes over 4 MFMAs and
// per-slot LDS traffic halves vs round 1. 4 slots (= 4 barriers) per step vs 9.
// h0_new(t) queue: double-buffered LDS (L0 state read + L1 input read share it).
// (Round 2 fix: no LDS-pointer arrays -> addrspacecast static-init error.)

typedef _Float16 f16;
typedef _Float16 f16x4 __attribute__((ext_vector_type(4)));
typedef _Float16 f16x8 __attribute__((ext_vector_type(8)));
typedef float f32x4 __attribute__((ext_vector_type(4)));

#define NSTEP 512
#define OFF_A0 0
#define OFF_A1 32768
#define OFF_AIO 65536
#define OFF_AX 98304
#define W_TOTAL 122880

// LDS byte offsets. hh buffers: [16 cols][136 f16] = 4352 B each.
#define HQ0 0
#define HQ1 4352
#define L0A 8704
#define L0B 13056
#define L1A 17408
#define L1B 21760
#define L1H 26112
#define XT 30464

__device__ __forceinline__ float rcp_f(float x) { return __builtin_amdgcn_rcpf(x); }
__device__ __forceinline__ float tanh_f(float x) {
  float e = __expf(2.f * x);
  return 1.f - 2.f * rcp_f(e + 1.f);
}
// sigmoid(t) for t in [-1,1] (t = tanh(...)): odd Taylor of 0.5+0.5*tanh(t/2), |err|<3e-6
__device__ __forceinline__ float sig_poly(float t) {
  float s = t * t;
  float p = fmaf(s, 2.1356861e-5f, -2.1081349e-4f);
  p = fmaf(s, p, 2.0833333e-3f);
  p = fmaf(s, p, -2.0833333e-2f);
  p = fmaf(s, p, 0.25f);
  return fmaf(t, p, 0.5f);
}

// Pack all recurrent-loop weights into f16 MFMA A-fragments.
// A-frag (16x16x32): A[m=lane&15][k=(lane>>4)*8+j], row-tile T = rows 16T..16T+15.
// A0 @0      [T8][sel2][kc4][lane64][j8]  sel0=Wg0 h-part, sel1=Wrec0
// A1 @32768  same                          sel0=Wg1 h-part, sel1=Wrec1
// AIO@65536  same                          sel0=Win1,       sel1=Wg1 x-part
// AX @98304  [T8][sel2][kc3][lane64][j8]  sel0=Win0,       sel1=Wg0 x-part (K=96)
__global__ __launch_bounds__(256) void prep_kernel(
    const float* __restrict__ Win0, const float* __restrict__ Wrec0,
    const float* __restrict__ Wg0, const float* __restrict__ Win1,
    const float* __restrict__ Wrec1, const float* __restrict__ Wg1,
    f16* __restrict__ W) {
  int i = blockIdx.x * 256 + threadIdx.x;
  if (i >= W_TOTAL) return;
  if (i < OFF_AX) {
    int sec = i >> 15;
    int r = i & 32767;
    int j = r & 7, lane = (r >> 3) & 63, kc = (r >> 9) & 3, sel = (r >> 11) & 1,
        w = (r >> 12) & 7;
    int row = w * 16 + (lane & 15);
    int k = kc * 32 + ((lane >> 4) << 3) + j;
    float v;
    if (sec == 0)
      v = sel ? Wrec0[row * 128 + k] : Wg0[row * 224 + 96 + k];
    else if (sec == 1)
      v = sel ? Wrec1[row * 128 + k] : Wg1[row * 256 + 128 + k];
    else
      v = sel ? Wg1[row * 256 + k] : Win1[row * 128 + k];
    W[i] = (f16)v;
  } else {
    int r = i - OFF_AX;
    int j = r & 7, lane = (r >> 3) & 63, g = r >> 9;
    int kc = g % 3, sg = g / 3;
    int sel = sg & 1, w = sg >> 1;
    int row = w * 16 + (lane & 15);
    int k = kc * 32 + ((lane >> 4) << 3) + j;
    W[i] = (f16)(sel ? Wg0[row * 224 + k] : Win0[row * 96 + k]);
  }
}

#define MFMA16(A, B, C) __builtin_amdgcn_mfma_f32_16x16x32_f16((A), (B), (C), 0, 0, 0)
#define ZERO4 ((f32x4){0.f, 0.f, 0.f, 0.f})

// 2-tile matvec accumulate: ga/ra[i2] += {awg,awr}[i2] * B-frag(SRC). One B-frag
// read feeds 4 MFMAs (the round-2 LDS amortization).
#define MM2(SRC)                                                    \
  {                                                                 \
    const f16* bp_ = (SRC) + c * 136 + 8 * q;                       \
    _Pragma("unroll") for (int kc_ = 0; kc_ < 4; ++kc_) {           \
      f16x8 bf_ = *(const f16x8*)(bp_ + kc_ * 32);                  \
      ga[0] = MFMA16(awg[0][kc_], bf_, ga[0]);                      \
      ra[0] = MFMA16(awr[0][kc_], bf_, ra[0]);                      \
      ga[1] = MFMA16(awg[1][kc_], bf_, ga[1]);                      \
      ra[1] = MFMA16(awr[1][kc_], bf_, ra[1]);                      \
    }                                                               \
  }

// io / input projection with the au/ag2 fragment set (KCN k-chunks) into ga/ra.
#define MMIO(SRC, KCN)                                              \
  {                                                                 \
    const f16* bp_ = (SRC) + c * 136 + 8 * q;                       \
    _Pragma("unroll") for (int kc_ = 0; kc_ < (KCN); ++kc_) {       \
      f16x8 bf_ = *(const f16x8*)(bp_ + kc_ * 32);                  \
      ga[0] = MFMA16(au[0][kc_], bf_, ga[0]);                       \
      ra[0] = MFMA16(ag2[0][kc_], bf_, ra[0]);                      \
      ga[1] = MFMA16(au[1][kc_], bf_, ga[1]);                       \
      ra[1] = MFMA16(ag2[1][kc_], bf_, ra[1]);                      \
    }                                                               \
  }

// RK stage body: gate math on 8 (gate,rec) pairs, ksum += WC*k, eval point
// hhc = h + HC*k, write f16 eval point to DST.
#define GATEALL(WC, HC, DST)                                        \
  _Pragma("unroll") for (int i2_ = 0; i2_ < 2; ++i2_) {             \
    f16x4 hv_;                                                      \
    _Pragma("unroll") for (int r_ = 0; r_ < 4; ++r_) {              \
      float th_ = tanh_f(ga[i2_][r_] + gx[i2_][r_]);                \
      float gt_ = sig_poly(th_);                                    \
      float kk_ = fmaf(gt_, ra[i2_][r_],                            \
                       fmaf(-itv[i2_][r_], hhc[i2_][r_], u[i2_][r_])); \
      ksum[i2_][r_] = fmaf((WC), kk_, ksum[i2_][r_]);               \
      float hn_ = fmaf((HC), kk_, hst[i2_][r_]);                    \
      hhc[i2_][r_] = hn_;                                           \
      hv_[r_] = (f16)hn_;                                           \
    }                                                               \
    *(f16x4*)((DST) + c * 136 + jb[i2_]) = hv_;                     \
  }

// RK stage 4: h_new = tanh(h + ksum/6), becomes both state and next stage-1 eval.
#define GATEFIN(DST)                                                \
  _Pragma("unroll") for (int i2_ = 0; i2_ < 2; ++i2_) {             \
    f16x4 hv_;                                                      \
    _Pragma("unroll") for (int r_ = 0; r_ < 4; ++r_) {              \
      float th_ = tanh_f(ga[i2_][r_] + gx[i2_][r_]);                \
      float gt_ = sig_poly(th_);                                    \
      float kk_ = fmaf(gt_, ra[i2_][r_],                            \
                       fmaf(-itv[i2_][r_], hhc[i2_][r_], u[i2_][r_])); \
      float ks_ = ksum[i2_][r_] + kk_;                              \
      float hn_ = tanh_f(fmaf(ks_, 0.16666667f, hst[i2_][r_]));     \
      hst[i2_][r_] = hn_;                                           \
      hhc[i2_][r_] = hn_;                                           \
      hv_[r_] = (f16)hn_;                                           \
    }                                                               \
    *(f16x4*)((DST) + c * 136 + jb[i2_]) = hv_;                     \
  }

#define ZACC { ga[0] = ZERO4; ra[0] = ZERO4; ga[1] = ZERO4; ra[1] = ZERO4; }

__global__ __launch_bounds__(512, 2) void ltc_kernel(
    const float* __restrict__ seq, const float* __restrict__ ctx,
    const float* __restrict__ tau0p, const float* __restrict__ bg0p,
    const float* __restrict__ tau1p, const float* __restrict__ bg1p,
    const float* __restrict__ W1, const float* __restrict__ b1,
    const float* __restrict__ W2, const float* __restrict__ b2,
    const f16* __restrict__ W, float* __restrict__ out) {
  __shared__ __align__(16) char smem[32768];
  f16* hq0 = (f16*)(smem + HQ0);
  f16* hq1 = (f16*)(smem + HQ1);
  f16* l0a = (f16*)(smem + L0A);
  f16* l0b = (f16*)(smem + L0B);
  f16* l1a = (f16*)(smem + L1A);
  f16* l1b = (f16*)(smem + L1B);
  f16* l1h = (f16*)(smem + L1H);
  f16* xt = (f16*)(smem + XT);

  const int tid = threadIdx.x;
  const int w8 = tid >> 6, lane = tid & 63;
  const int q = lane >> 4, c = lane & 15;
  const int wl = w8 & 3;
  const bool isL0 = (w8 < 4);
  const int bg = blockIdx.x;
  int jb[2];
  jb[0] = 32 * wl + 4 * q;
  jb[1] = jb[0] + 16;

  f16* bufA = isL0 ? l0a : l1a;
  f16* bufB = isL0 ? l0b : l1b;

  // ---- weight fragments -> VGPRs (held for whole kernel) ----
  // awg/awr: recurrent gate-h / rec tiles. au/ag2: L0 -> (Win0, Wg0x) K=96;
  // L1 -> (Win1, Wg1x) K=128. Unified names keep L0/L1 register budgets shared.
  f16x8 awg[2][4], awr[2][4], au[2][4], ag2[2][4];
  f16x8 bctx;
  if (isL0) {
#pragma unroll
    for (int i2 = 0; i2 < 2; ++i2) {
      int T = 2 * wl + i2;
#pragma unroll
      for (int kc = 0; kc < 4; ++kc) {
        awg[i2][kc] = *(const f16x8*)(W + OFF_A0 + (((T * 2 + 0) * 4 + kc) * 64 + lane) * 8);
        awr[i2][kc] = *(const f16x8*)(W + OFF_A0 + (((T * 2 + 1) * 4 + kc) * 64 + lane) * 8);
      }
#pragma unroll
      for (int kc = 0; kc < 3; ++kc) {
        au[i2][kc] = *(const f16x8*)(W + OFF_AX + (((T * 2 + 0) * 3 + kc) * 64 + lane) * 8);
        ag2[i2][kc] = *(const f16x8*)(W + OFF_AX + (((T * 2 + 1) * 3 + kc) * 64 + lane) * 8);
      }
      au[i2][3] = (f16x8)(f16)0.f;
      ag2[i2][3] = (f16x8)(f16)0.f;
    }
    const float* cp = ctx + (bg * 16 + c) * 32 + 8 * q;
#pragma unroll
    for (int j = 0; j < 8; ++j) bctx[j] = (f16)cp[j];
  } else {
#pragma unroll
    for (int i2 = 0; i2 < 2; ++i2) {
      int T = 2 * wl + i2;
#pragma unroll
      for (int kc = 0; kc < 4; ++kc) {
        awg[i2][kc] = *(const f16x8*)(W + OFF_A1 + (((T * 2 + 0) * 4 + kc) * 64 + lane) * 8);
        awr[i2][kc] = *(const f16x8*)(W + OFF_A1 + (((T * 2 + 1) * 4 + kc) * 64 + lane) * 8);
        au[i2][kc] = *(const f16x8*)(W + OFF_AIO + (((T * 2 + 0) * 4 + kc) * 64 + lane) * 8);
        ag2[i2][kc] = *(const f16x8*)(W + OFF_AIO + (((T * 2 + 1) * 4 + kc) * 64 + lane) * 8);
      }
    }
  }

  // per-lane params for the 8 owned rows
  const float* taup = isL0 ? tau0p : tau1p;
  const float* bgp = isL0 ? bg0p : bg1p;
  f32x4 itv[2], bgv[2];
#pragma unroll
  for (int i2 = 0; i2 < 2; ++i2)
#pragma unroll
    for (int r = 0; r < 4; ++r) {
      float t = taup[jb[i2] + r];
      itv[i2][r] = 1.f / (logf(1.f + __expf(t)) + 1.f);  // 1/(softplus+1)
      bgv[i2][r] = bgp[jb[i2] + r];
    }

  f32x4 hst[2], hhc[2], u[2], gx[2], ksum[2], ga[2], ra[2];
  hst[0] = hst[1] = hhc[0] = hhc[1] = ZERO4;
  ksum[0] = ksum[1] = ZERO4;

  // zero initial-state buffers: hq1 (h0 at t=-1) and l1h (h1 at t=-1)
  for (int j = tid; j < 2176; j += 512) {
    hq1[j] = (f16)0.f;
    l1h[j] = (f16)0.f;
  }
  // pre-stage x(0): 256 L0 threads, float4 each
  const int bs = tid >> 4, fp = tid & 15;
  const size_t seqrow = ((size_t)(bg * 16 + bs)) * NSTEP * 64 + 4 * fp;
  if (tid < 256) {
    float4 sv = *(const float4*)(seq + seqrow);
    *(f16x4*)(xt + bs * 72 + 4 * fp) =
        (f16x4){(f16)sv.x, (f16)sv.y, (f16)sv.z, (f16)sv.w};
  }
  __syncthreads();

  float4 sqv = {0.f, 0.f, 0.f, 0.f};

#pragma unroll 1
  for (int i = 0; i <= NSTEP; ++i) {
    const f16* hprev = ((i + 1) & 1) ? hq1 : hq0;  // h0(t-1) buffer

    // ===== slot A: L0 x-proj + stage1 | L1 io-proj + stage1 =====
    if (isL0) {
      if (i < NSTEP) {
        if (i + 1 < NSTEP) sqv = *(const float4*)(seq + seqrow + (size_t)(i + 1) * 64);
        ZACC;
        {  // x projection: u = Win0*x, gx = Wg0x*x (K=96: 2 chunks from xt + ctx)
          f16x8 bx0 = *(const f16x8*)(xt + c * 72 + 8 * q);
          f16x8 bx1 = *(const f16x8*)(xt + c * 72 + 32 + 8 * q);
#pragma unroll
          for (int i2 = 0; i2 < 2; ++i2) {
            ga[i2] = MFMA16(au[i2][0], bx0, ga[i2]);
            ra[i2] = MFMA16(ag2[i2][0], bx0, ra[i2]);
            ga[i2] = MFMA16(au[i2][1], bx1, ga[i2]);
            ra[i2] = MFMA16(ag2[i2][1], bx1, ra[i2]);
            ga[i2] = MFMA16(au[i2][2], bctx, ga[i2]);
            ra[i2] = MFMA16(ag2[i2][2], bctx, ra[i2]);
          }
        }
#pragma unroll
        for (int i2 = 0; i2 < 2; ++i2) {
          u[i2] = ga[i2];
#pragma unroll
          for (int r = 0; r < 4; ++r) gx[i2][r] = ra[i2][r] + bgv[i2][r];
        }
        ZACC;
        MM2(hprev);  // stage 1 on h0(t-1)
        ksum[0] = ZERO4; ksum[1] = ZERO4;
        GATEALL(1.0f, 0.5f, bufA);
      }
    } else {
      if (i >= 1) {
        ZACC;
        MMIO(hprev, 4);  // u1 = Win1*h0_new, g1x = Wg1x*h0_new
#pragma unroll
        for (int i2 = 0; i2 < 2; ++i2) {
          u[i2] = ga[i2];
#pragma unroll
          for (int r = 0; r < 4; ++r) gx[i2][r] = ra[i2][r] + bgv[i2][r];
        }
        ZACC;
        MM2(l1h);  // stage 1 on h1(t-2)
        ksum[0] = ZERO4; ksum[1] = ZERO4;
        GATEALL(1.0f, 0.5f, bufA);
      }
    }
    __syncthreads();

    // ===== slot B: stage 2 =====
    if ((isL0 && i < NSTEP) || (!isL0 && i >= 1)) {
      ZACC;
      MM2(bufA);
      GATEALL(2.0f, 0.5f, bufB);
    }
    __syncthreads();

    // ===== slot C: stage 3 =====
    if ((isL0 && i < NSTEP) || (!isL0 && i >= 1)) {
      ZACC;
      MM2(bufB);
      GATEALL(2.0f, 1.0f, bufA);
    }
    __syncthreads();

    // ===== slot D: stage 4 -> h_new; L0 stages x(i+1) =====
    if (isL0) {
      if (i < NSTEP) {
        ZACC;
        MM2(bufA);
        GATEFIN((i & 1) ? hq1 : hq0);
        if (tid < 256 && i + 1 < NSTEP)
          *(f16x4*)(xt + bs * 72 + 4 * fp) =
              (f16x4){(f16)sqv.x, (f16)sqv.y, (f16)sqv.z, (f16)sqv.w};
      }
    } else {
      if (i >= 1) {
        ZACC;
        MM2(bufA);
        GATEFIN(l1h);
      }
    }
    __syncthreads();
  }

  // ======================= classifier epilogue ===========================
  float* h1f = (float*)smem;  // [16][132] f32
  if (!isL0) {
#pragma unroll
    for (int i2 = 0; i2 < 2; ++i2)
      *(f32x4*)(h1f + c * 132 + jb[i2]) = hst[i2];
  }
  __syncthreads();
  float* z1 = (float*)(smem + 16 * 132 * 4);  // [16][64] f32
  {
    int b = tid >> 5, o = tid & 31;
#pragma unroll
    for (int hlf = 0; hlf < 2; ++hlf) {
      int oo = o + 32 * hlf;
      const float* wr = W1 + oo * 128;
      const float* hr = h1f + b * 132;
      float s = 0.f;
#pragma unroll
      for (int j = 0; j < 128; j += 4) {
        f32x4 wv = *(const f32x4*)(wr + j);
        f32x4 hv = *(const f32x4*)(hr + j);
        s += wv[0] * hv[0] + wv[1] * hv[1] + wv[2] * hv[2] + wv[3] * hv[3];
      }
      s += b1[oo];
      z1[b * 64 + oo] = fmaxf(s, 0.f);
    }
  }
  __syncthreads();
  if (tid < 16) {
    float s = b2[0];
#pragma unroll
    for (int o = 0; o < 64; ++o) s += z1[tid * 64 + o] * W2[o];
    out[bg * 16 + tid] = rcp_f(1.f + __expf(-s));
  }
}

extern "C" void kernel_launch(void* const* d_in, const int* in_sizes, int n_in,
                              void* d_out, int out_size, void* d_ws, size_t ws_size,
                              hipStream_t stream) {
  (void)in_sizes; (void)n_in; (void)out_size; (void)ws_size;
  const float* seq = (const float*)d_in[0];
  const float* ctx = (const float*)d_in[1];
  const float* tau0 = (const float*)d_in[2];
  const float* Win0 = (const float*)d_in[3];
  const float* Wrec0 = (const float*)d_in[4];
  const float* Wg0 = (const float*)d_in[5];
  const float* bg0 = (const float*)d_in[6];
  const float* tau1 = (const float*)d_in[7];
  const float* Win1 = (const float*)d_in[8];
  const float* Wrec1 = (const float*)d_in[9];
  const float* Wg1 = (const float*)d_in[10];
  const float* bg1 = (const float*)d_in[11];
  const float* W1 = (const float*)d_in[12];
  const float* b1 = (const float*)d_in[13];
  const float* W2 = (const float*)d_in[14];
  const float* b2 = (const float*)d_in[15];
  f16* W = (f16*)d_ws;  // 245760 B of packed fragments

  prep_kernel<<<480, 256, 0, stream>>>(Win0, Wrec0, Wg0, Win1, Wrec1, Wg1, W);
  ltc_kernel<<<32, 512, 0, stream>>>(seq, ctx, tau0, bg0, tau1, bg1, W1, b1, W2,
                                     b2, W, (float*)d_out);
}